// Round 22
// baseline (120.601 us; speedup 1.0000x reference)
//
#include <hip/hip_runtime.h>

typedef __bf16 bf16;
typedef __attribute__((ext_vector_type(8))) __bf16 bf16x8;
typedef __attribute__((ext_vector_type(8))) ushort ushort8v;
typedef __attribute__((ext_vector_type(4))) ushort ushort4v;
typedef __attribute__((ext_vector_type(16))) float f32x16;

constexpr int S_LEN = 2048;
constexpr int DH    = 64;
constexpr int QBLK  = 128;                       // 4 waves x 32 q-rows
constexpr int KVBLK = 64;                        // compute granule
constexpr int NWAVE = 4;
constexpr int NT    = S_LEN / KVBLK;             // 32 kv tiles (flag granule)
constexpr int NT2   = NT / 2;                    // 16 staged double-tiles
constexpr float QSCALE = 0.125f * 1.44269504088896f;  // 1/sqrt(64) * log2(e)
constexpr float NEG    = -1.44269504e9f;         // -1e9 in log2 domain
constexpr float THR    = 8.0f;                   // defer-max threshold (T13)
constexpr size_t TILE_BYTES = (size_t)KVBLK * DH * 2;       // 8 KiB
constexpr size_t KV_BYTES   = (size_t)64 * NT * TILE_BYTES; // 16 MiB per tensor

__device__ __forceinline__ ushort bfb(float f) {
  bf16 b = (bf16)f;
  return __builtin_bit_cast(ushort, b);
}
__device__ __forceinline__ int SWZ(int row) {
  return ((row & 7) ^ ((row >> 3) & 7)) << 4;
}
__device__ __forceinline__ uint cvtpk(float lo, float hi) {
  uint r;
  asm("v_cvt_pk_bf16_f32 %0, %1, %2" : "=v"(r) : "v"(lo), "v"(hi));
  return r;
}
__device__ __forceinline__ void gload16(const char* g, void* l) {
  __builtin_amdgcn_global_load_lds(
      (__attribute__((address_space(1))) void*)(g),
      (__attribute__((address_space(3))) void*)(l), 16, 0, 0);
}

// ---- fused prepass: K/V -> bf16 swizzled tile blobs; blocks with bh<8 also
// compute mask flags F[qt*8+g] (disjoint words, no atomics, no memset). ----
__global__ __launch_bounds__(256)
void cvt_kv(const float* __restrict__ K, const float* __restrict__ V,
            const int* __restrict__ M, char* __restrict__ kws,
            char* __restrict__ vws, uint* __restrict__ F) {
  const int t = blockIdx.x, bh = blockIdx.y, tid = threadIdx.x;
  const float* Kb = K + ((size_t)bh * S_LEN + t * KVBLK) * DH;
  const float* Vb = V + ((size_t)bh * S_LEN + t * KVBLK) * DH;
  char* kd = kws + ((size_t)bh * NT + t) * TILE_BYTES;
  char* vd = vws + ((size_t)bh * NT + t) * TILE_BYTES;

  const int kr0 = tid >> 3, kc8 = tid & 7;
#pragma unroll
  for (int h = 0; h < 2; ++h) {
    const int row = kr0 + 32 * h;
    const float* kp = Kb + (size_t)row * DH + kc8 * 8;
    float4 a = *(const float4*)kp;
    float4 b = *(const float4*)(kp + 4);
    ushort8v pk;
    pk[0]=bfb(a.x); pk[1]=bfb(a.y); pk[2]=bfb(a.z); pk[3]=bfb(a.w);
    pk[4]=bfb(b.x); pk[5]=bfb(b.y); pk[6]=bfb(b.z); pk[7]=bfb(b.w);
    *(ushort8v*)(kd + row * 128 + ((kc8 * 16) ^ SWZ(row))) = pk;
  }
  const int vr = (tid >> 4) * 4, vc = (tid & 15) * 4;
  float rr[4][4];
#pragma unroll
  for (int i = 0; i < 4; ++i)
    *(float4*)rr[i] = *(const float4*)(Vb + (size_t)(vr + i) * DH + vc);
#pragma unroll
  for (int c = 0; c < 4; ++c) {
    const int d = vc + c;
    ushort4v p4;
    p4[0]=bfb(rr[0][c]); p4[1]=bfb(rr[1][c]);
    p4[2]=bfb(rr[2][c]); p4[3]=bfb(rr[3][c]);
    *(ushort4v*)(vd + d * 128 + ((vr * 2) ^ SWZ(d))) = p4;
  }

  // ---- mask flags for (qt=t, group g=bh): block-uniform branch ----
  if (bh < 8) {
    const int qt = t, g = bh;
    const int r  = tid >> 2;
    const int c0 = (tid & 3) * 16;
    __shared__ int s[4];
    uint bits = 0;
    for (int i = 0; i < 4; ++i) {
      const int kt = g * 4 + i;
      const int* row = M + (size_t)(qt * 64 + r) * S_LEN + kt * 64 + c0;
      int ok = 1;
#pragma unroll
      for (int j = 0; j < 4; ++j) {
        int4 v = *(const int4*)(row + j * 4);
        ok &= (v.x != 0) & (v.y != 0) & (v.z != 0) & (v.w != 0);
      }
      ok = __all(ok) ? 1 : 0;
      if ((tid & 63) == 0) s[tid >> 6] = ok;
      __syncthreads();
      if (s[0] & s[1] & s[2] & s[3]) bits |= 1u << kt;
      __syncthreads();
    }
    if (tid == 0) F[qt * 8 + g] = bits;
  }
}

// ---- main: R16 compute body; staging coarsened to 128-kv double-tiles ----
// 32 KB LDS (cap 5 wg/CU >= supplied 4); barriers halved (32/block);
// two sequential 64-kv compute halves keep register pressure at R16 level.
template<bool PRE>
__global__ __launch_bounds__(256, 3)
void attn_fwd(const float* __restrict__ Q, const float* __restrict__ K,
              const float* __restrict__ V, const int* __restrict__ M,
              const uint* __restrict__ F, const char* __restrict__ kws,
              const char* __restrict__ vws, float* __restrict__ O)
{
  __shared__ __align__(16) ushort kb[2 * KVBLK * DH];    // 2 tiles, swizzled
  __shared__ __align__(16) ushort vb[2 * KVBLK * DH];

  const int tid  = threadIdx.x;
  const int lane = tid & 63;
  const int w    = tid >> 6;
  const int ql   = lane & 31;   // q within wave block; MFMA row/col index
  const int h    = lane >> 5;   // lane half

  // XCD-aware bijective block swizzle (1024 % 8 == 0)
  const int flat = blockIdx.y * gridDim.x + blockIdx.x;
  const int nid  = (flat & 7) * 128 + (flat >> 3);
  const int q0   = (nid & 15) * QBLK;
  const int bh   = nid >> 4;

  const float* Qb = Q + ((size_t)bh * S_LEN) * DH;
  const float* Kb = K + ((size_t)bh * S_LEN) * DH;
  const float* Vb = V + ((size_t)bh * S_LEN) * DH;

  // combine disjoint flag words: OR groups per 64-row half, AND both halves
  uint fmask = 0u;
  if (PRE) {
    uint fm0 = 0u, fm1 = 0u;
#pragma unroll
    for (int g = 0; g < 8; ++g) {
      fm0 |= F[(q0 >> 6) * 8 + g];
      fm1 |= F[((q0 >> 6) + 1) * 8 + g];
    }
    fmask = fm0 & fm1;
  }

  // ---- Q fragments (B-operand): qf[s] = Q[q][16s+8h+j]*QSCALE ----
  bf16x8 qf[4];
  {
    const float* qp = Qb + (size_t)(q0 + w * 32 + ql) * DH + 8 * h;
#pragma unroll
    for (int s = 0; s < 4; ++s) {
      float4 a = *(const float4*)(qp + 16 * s);
      float4 b = *(const float4*)(qp + 16 * s + 4);
      bf16x8 t2;
      t2[0]=(bf16)(a.x*QSCALE); t2[1]=(bf16)(a.y*QSCALE);
      t2[2]=(bf16)(a.z*QSCALE); t2[3]=(bf16)(a.w*QSCALE);
      t2[4]=(bf16)(b.x*QSCALE); t2[5]=(bf16)(b.y*QSCALE);
      t2[6]=(bf16)(b.z*QSCALE); t2[7]=(bf16)(b.w*QSCALE);
      qf[s] = t2;
    }
  }

  f32x16 acc0, acc1;            // O^T d-tiles 0,1
#pragma unroll
  for (int i = 0; i < 16; ++i) { acc0[i] = 0.f; acc1[i] = 0.f; }
  float mrow = -1e30f;
  float rsum = 0.f;

  // LDS byte offsets: row = 32x+ql, col byte 32s+16h (same for K and V)
  int kofs[2][4];
#pragma unroll
  for (int x = 0; x < 2; ++x) {
    const int row = 32 * x + ql;
    const int sw  = SWZ(row);
#pragma unroll
    for (int s = 0; s < 4; ++s)
      kofs[x][s] = row * 128 + ((32 * s + 16 * h) ^ sw);
  }

  // P-pack: 8 exp'd scores -> PV B-frag via lane+-32 exchange (T12)
  auto mkfrag = [&](float p0, float p1, float p2, float p3,
                    float p4, float p5, float p6, float p7) -> bf16x8 {
    uint a0 = cvtpk(p0, p1), a1 = cvtpk(p2, p3);
    uint b0 = cvtpk(p4, p5), b1 = cvtpk(p6, p7);
    uint ta0 = __shfl_xor(a0, 32), ta1 = __shfl_xor(a1, 32);
    uint tb0 = __shfl_xor(b0, 32), tb1 = __shfl_xor(b1, 32);
    uint4 wv;
    wv.x = h ? tb0 : a0;
    wv.y = h ? tb1 : a1;
    wv.z = h ? b0  : ta0;
    wv.w = h ? b1  : ta1;
    return __builtin_bit_cast(bf16x8, wv);
  };

  // ---- 64-kv compute half (identical to R16 body); base = LDS byte base ----
  auto compute = [&](int t64, int base) {
    f32x16 sc0, sc1;
#pragma unroll
    for (int i = 0; i < 16; ++i) { sc0[i] = 0.f; sc1[i] = 0.f; }

    __builtin_amdgcn_s_setprio(1);
#pragma unroll
    for (int s = 0; s < 4; ++s) {
      bf16x8 k0 = *(const bf16x8*)((const char*)kb + base + kofs[0][s]);
      bf16x8 k1 = *(const bf16x8*)((const char*)kb + base + kofs[1][s]);
      sc0 = __builtin_amdgcn_mfma_f32_32x32x16_bf16(k0, qf[s], sc0, 0,0,0);
      sc1 = __builtin_amdgcn_mfma_f32_32x32x16_bf16(k1, qf[s], sc1, 0,0,0);
    }
    __builtin_amdgcn_s_setprio(0);

    const bool allset = PRE ? (((fmask >> t64) & 1u) != 0u) : false;
    if (!allset) {
      const size_t mo = (size_t)(q0 + w * 32 + ql) * S_LEN + t64 * KVBLK + 4 * h;
#pragma unroll
      for (int r = 0; r < 16; ++r) {
        const int cr = (r & 3) + 8 * (r >> 2);
        if (M[mo + cr] == 0)      sc0[r] = NEG;
        if (M[mo + 32 + cr] == 0) sc1[r] = NEG;
      }
    }

    // in-register online softmax (serial chain — R16 form)
    float lm = fmaxf(sc0[0], sc0[1]);
#pragma unroll
    for (int i = 2; i < 16; ++i) lm = fmaxf(lm, sc0[i]);
#pragma unroll
    for (int i = 0; i < 16; ++i) lm = fmaxf(lm, sc1[i]);
    lm = fmaxf(lm, __shfl_xor(lm, 32));

    if (!__all(lm - mrow <= THR)) {      // defer-max (T13)
      const float mnew = fmaxf(mrow, lm);
      const float corr = __builtin_amdgcn_exp2f(mrow - mnew);
      rsum *= corr;
      acc0 *= corr;
      acc1 *= corr;
      mrow = mnew;
    }

    float ps = 0.f;
#pragma unroll
    for (int i = 0; i < 16; ++i) {
      sc0[i] = __builtin_amdgcn_exp2f(sc0[i] - mrow); ps += sc0[i];
      sc1[i] = __builtin_amdgcn_exp2f(sc1[i] - mrow); ps += sc1[i];
    }
    rsum += ps;

    bf16x8 pf[4];
    pf[0] = mkfrag(sc0[0], sc0[1], sc0[2],  sc0[3],  sc0[4],  sc0[5],  sc0[6],  sc0[7]);
    pf[1] = mkfrag(sc0[8], sc0[9], sc0[10], sc0[11], sc0[12], sc0[13], sc0[14], sc0[15]);
    pf[2] = mkfrag(sc1[0], sc1[1], sc1[2],  sc1[3],  sc1[4],  sc1[5],  sc1[6],  sc1[7]);
    pf[3] = mkfrag(sc1[8], sc1[9], sc1[10], sc1[11], sc1[12], sc1[13], sc1[14], sc1[15]);

    __builtin_amdgcn_s_setprio(1);
#pragma unroll
    for (int s = 0; s < 4; ++s) {
      bf16x8 v0 = *(const bf16x8*)((const char*)vb + base + kofs[0][s]);
      bf16x8 v1 = *(const bf16x8*)((const char*)vb + base + kofs[1][s]);
      acc0 = __builtin_amdgcn_mfma_f32_32x32x16_bf16(v0, pf[s], acc0, 0,0,0);
      acc1 = __builtin_amdgcn_mfma_f32_32x32x16_bf16(v1, pf[s], acc1, 0,0,0);
    }
    __builtin_amdgcn_s_setprio(0);
  };

  // staging decomposition (fallback path)
  const int kr0 = tid >> 3, kc8 = tid & 7;
  const int vr = (tid >> 4) * 4, vc = (tid & 15) * 4;

  if constexpr (PRE) {
    for (int tt = 0; tt < NT2; ++tt) {
      // ---- stage double-tile (2x8 KB contiguous blobs), 8 loads/thread ----
      const char* ksrc = kws + ((size_t)bh * NT + 2 * tt) * TILE_BYTES;
      const char* vsrc = vws + ((size_t)bh * NT + 2 * tt) * TILE_BYTES;
#pragma unroll
      for (int c = 0; c < 4; ++c) {
        const int off = (w + c * 4) * 1024 + lane * 16;
        gload16(ksrc + off, (char*)kb + off);
        gload16(vsrc + off, (char*)vb + off);
      }
      __syncthreads();
      compute(2 * tt,     0);
      compute(2 * tt + 1, 8192);
      __syncthreads();
    }
  } else {
    for (int t = 0; t < NT; ++t) {
#pragma unroll
      for (int hh = 0; hh < 2; ++hh) {
        const int row = kr0 + 32 * hh;
        const float* kp = Kb + (size_t)(t * KVBLK + row) * DH + kc8 * 8;
        float4 a = *(const float4*)kp;
        float4 b = *(const float4*)(kp + 4);
        ushort8v pk;
        pk[0]=bfb(a.x); pk[1]=bfb(a.y); pk[2]=bfb(a.z); pk[3]=bfb(a.w);
        pk[4]=bfb(b.x); pk[5]=bfb(b.y); pk[6]=bfb(b.z); pk[7]=bfb(b.w);
        *(ushort8v*)((char*)kb + row * 128 + ((kc8 * 16) ^ SWZ(row))) = pk;
      }
      float rr[4][4];
#pragma unroll
      for (int i = 0; i < 4; ++i)
        *(float4*)rr[i] = *(const float4*)(Vb + (size_t)(t * KVBLK + vr + i) * DH + vc);
#pragma unroll
      for (int c = 0; c < 4; ++c) {
        const int d = vc + c;
        ushort4v p4;
        p4[0]=bfb(rr[0][c]); p4[1]=bfb(rr[1][c]);
        p4[2]=bfb(rr[2][c]); p4[3]=bfb(rr[3][c]);
        *(ushort4v*)((char*)vb + d * 128 + ((vr * 2) ^ SWZ(d))) = p4;
      }
      __syncthreads();
      compute(t, 0);
      __syncthreads();
    }
  }

  // ---- epilogue: O[q][d] = acc / rsum ----
  rsum += __shfl_xor(rsum, 32);
  const float inv = 1.0f / rsum;
  float* Ob = O + ((size_t)bh * S_LEN + q0 + w * 32 + ql) * DH + 4 * h;
#pragma unroll
  for (int g = 0; g < 4; ++g) {
    float4 o0 = { acc0[4*g+0]*inv, acc0[4*g+1]*inv, acc0[4*g+2]*inv, acc0[4*g+3]*inv };
    float4 o1 = { acc1[4*g+0]*inv, acc1[4*g+1]*inv, acc1[4*g+2]*inv, acc1[4*g+3]*inv };
    *(float4*)(Ob + 8 * g)      = o0;
    *(float4*)(Ob + 32 + 8 * g) = o1;
  }
}

extern "C" void kernel_launch(void* const* d_in, const int* in_sizes, int n_in,
                              void* d_out, int out_size, void* d_ws, size_t ws_size,
                              hipStream_t stream)
{
  const float* Q = (const float*)d_in[0];
  const float* K = (const float*)d_in[1];
  const float* V = (const float*)d_in[2];
  const int*   M = (const int*)d_in[3];
  float* O = (float*)d_out;

  const size_t need = 4096 + 2 * KV_BYTES;
  const bool pre = (d_ws != nullptr) && (ws_size >= need);

  dim3 grid(S_LEN / QBLK, 4 * 16);   // 16 q-blocks x 64 (b,h) = 1024 wgs
  if (pre) {
    uint* F   = (uint*)d_ws;          // 32*8 disjoint words, fully overwritten
    char* kws = (char*)d_ws + 4096;
    char* vws = kws + KV_BYTES;
    cvt_kv<<<dim3(NT, 64), 256, 0, stream>>>(K, V, M, kws, vws, F);
    attn_fwd<true><<<grid, NWAVE * 64, 0, stream>>>(Q, K, V, M, F, kws, vws, O);
  } else {
    attn_fwd<false><<<grid, NWAVE * 64, 0, stream>>>(Q, K, V, M, nullptr, nullptr, nullptr, O);
  }
}

// Round 23
// 114.526 us; speedup vs baseline: 1.0530x; 1.0530x over previous
//
#include <hip/hip_runtime.h>

typedef __bf16 bf16;
typedef __attribute__((ext_vector_type(8))) __bf16 bf16x8;
typedef __attribute__((ext_vector_type(8))) ushort ushort8v;
typedef __attribute__((ext_vector_type(4))) ushort ushort4v;
typedef __attribute__((ext_vector_type(16))) float f32x16;

constexpr int S_LEN = 2048;
constexpr int DH    = 64;
constexpr int QBLK  = 128;                       // 4 waves x 32 q-rows
constexpr int KVBLK = 64;
constexpr int NWAVE = 4;
constexpr int NT    = S_LEN / KVBLK;             // 32 kv tiles
constexpr float QSCALE = 0.125f * 1.44269504088896f;  // 1/sqrt(64) * log2(e)
constexpr float NEG    = -1.44269504e9f;         // -1e9 in log2 domain
constexpr float THR    = 8.0f;                   // defer-max threshold (T13)
constexpr size_t TILE_BYTES = (size_t)KVBLK * DH * 2;       // 8 KiB
constexpr size_t KV_BYTES   = (size_t)64 * NT * TILE_BYTES; // 16 MiB per tensor

__device__ __forceinline__ ushort bfb(float f) {
  bf16 b = (bf16)f;
  return __builtin_bit_cast(ushort, b);
}
__device__ __forceinline__ int SWZ(int row) {
  return ((row & 7) ^ ((row >> 3) & 7)) << 4;
}
__device__ __forceinline__ uint cvtpk(float lo, float hi) {
  uint r;
  asm("v_cvt_pk_bf16_f32 %0, %1, %2" : "=v"(r) : "v"(lo), "v"(hi));
  return r;
}
__device__ __forceinline__ void gload16(const char* g, void* l) {
  __builtin_amdgcn_global_load_lds(
      (__attribute__((address_space(1))) void*)(g),
      (__attribute__((address_space(3))) void*)(l), 16, 0, 0);
}

// ---- fused prepass: K/V -> bf16 swizzled tile blobs; blocks with bh<8 also
// compute mask flags F[qt*8+g] (disjoint words, no atomics, no memset). ----
__global__ __launch_bounds__(256)
void cvt_kv(const float* __restrict__ K, const float* __restrict__ V,
            const int* __restrict__ M, char* __restrict__ kws,
            char* __restrict__ vws, uint* __restrict__ F) {
  const int t = blockIdx.x, bh = blockIdx.y, tid = threadIdx.x;
  const float* Kb = K + ((size_t)bh * S_LEN + t * KVBLK) * DH;
  const float* Vb = V + ((size_t)bh * S_LEN + t * KVBLK) * DH;
  char* kd = kws + ((size_t)bh * NT + t) * TILE_BYTES;
  char* vd = vws + ((size_t)bh * NT + t) * TILE_BYTES;

  const int kr0 = tid >> 3, kc8 = tid & 7;
#pragma unroll
  for (int h = 0; h < 2; ++h) {
    const int row = kr0 + 32 * h;
    const float* kp = Kb + (size_t)row * DH + kc8 * 8;
    float4 a = *(const float4*)kp;
    float4 b = *(const float4*)(kp + 4);
    ushort8v pk;
    pk[0]=bfb(a.x); pk[1]=bfb(a.y); pk[2]=bfb(a.z); pk[3]=bfb(a.w);
    pk[4]=bfb(b.x); pk[5]=bfb(b.y); pk[6]=bfb(b.z); pk[7]=bfb(b.w);
    *(ushort8v*)(kd + row * 128 + ((kc8 * 16) ^ SWZ(row))) = pk;
  }
  const int vr = (tid >> 4) * 4, vc = (tid & 15) * 4;
  float rr[4][4];
#pragma unroll
  for (int i = 0; i < 4; ++i)
    *(float4*)rr[i] = *(const float4*)(Vb + (size_t)(vr + i) * DH + vc);
#pragma unroll
  for (int c = 0; c < 4; ++c) {
    const int d = vc + c;
    ushort4v p4;
    p4[0]=bfb(rr[0][c]); p4[1]=bfb(rr[1][c]);
    p4[2]=bfb(rr[2][c]); p4[3]=bfb(rr[3][c]);
    *(ushort4v*)(vd + d * 128 + ((vr * 2) ^ SWZ(d))) = p4;
  }

  // ---- mask flags for (qt=t, group g=bh): block-uniform branch ----
  if (bh < 8) {
    const int qt = t, g = bh;
    const int r  = tid >> 2;
    const int c0 = (tid & 3) * 16;
    __shared__ int s[4];
    uint bits = 0;
    for (int i = 0; i < 4; ++i) {
      const int kt = g * 4 + i;
      const int* row = M + (size_t)(qt * 64 + r) * S_LEN + kt * 64 + c0;
      int ok = 1;
#pragma unroll
      for (int j = 0; j < 4; ++j) {
        int4 v = *(const int4*)(row + j * 4);
        ok &= (v.x != 0) & (v.y != 0) & (v.z != 0) & (v.w != 0);
      }
      ok = __all(ok) ? 1 : 0;
      if ((tid & 63) == 0) s[tid >> 6] = ok;
      __syncthreads();
      if (s[0] & s[1] & s[2] & s[3]) bits |= 1u << kt;
      __syncthreads();
    }
    if (tid == 0) F[qt * 8 + g] = bits;
  }
}

// ---- main: champion (R16/R21) — 32x32 MFMA, in-register P (T12),
// single-buffer LDS (16 KB), VGPR 60, serial max chain. ----
template<bool PRE>
__global__ __launch_bounds__(256, 4)
void attn_fwd(const float* __restrict__ Q, const float* __restrict__ K,
              const float* __restrict__ V, const int* __restrict__ M,
              const uint* __restrict__ F, const char* __restrict__ kws,
              const char* __restrict__ vws, float* __restrict__ O)
{
  __shared__ __align__(16) ushort kb[KVBLK * DH];        // [kv][d] swizzled
  __shared__ __align__(16) ushort vb[KVBLK * DH];        // [d][kv] swizzled

  const int tid  = threadIdx.x;
  const int lane = tid & 63;
  const int w    = tid >> 6;
  const int ql   = lane & 31;   // q within wave block; MFMA row/col index
  const int h    = lane >> 5;   // lane half

  // XCD-aware bijective block swizzle (1024 % 8 == 0)
  const int flat = blockIdx.y * gridDim.x + blockIdx.x;
  const int nid  = (flat & 7) * 128 + (flat >> 3);
  const int q0   = (nid & 15) * QBLK;
  const int bh   = nid >> 4;

  const float* Qb = Q + ((size_t)bh * S_LEN) * DH;
  const float* Kb = K + ((size_t)bh * S_LEN) * DH;
  const float* Vb = V + ((size_t)bh * S_LEN) * DH;

  // combine disjoint flag words: OR groups per 64-row half, AND both halves
  uint fmask = 0u;
  if (PRE) {
    uint fm0 = 0u, fm1 = 0u;
#pragma unroll
    for (int g = 0; g < 8; ++g) {
      fm0 |= F[(q0 >> 6) * 8 + g];
      fm1 |= F[((q0 >> 6) + 1) * 8 + g];
    }
    fmask = fm0 & fm1;
  }

  // ---- Q fragments (B-operand): qf[s] = Q[q][16s+8h+j]*QSCALE ----
  bf16x8 qf[4];
  {
    const float* qp = Qb + (size_t)(q0 + w * 32 + ql) * DH + 8 * h;
#pragma unroll
    for (int s = 0; s < 4; ++s) {
      float4 a = *(const float4*)(qp + 16 * s);
      float4 b = *(const float4*)(qp + 16 * s + 4);
      bf16x8 t2;
      t2[0]=(bf16)(a.x*QSCALE); t2[1]=(bf16)(a.y*QSCALE);
      t2[2]=(bf16)(a.z*QSCALE); t2[3]=(bf16)(a.w*QSCALE);
      t2[4]=(bf16)(b.x*QSCALE); t2[5]=(bf16)(b.y*QSCALE);
      t2[6]=(bf16)(b.z*QSCALE); t2[7]=(bf16)(b.w*QSCALE);
      qf[s] = t2;
    }
  }

  f32x16 acc0, acc1;            // O^T d-tiles 0,1
#pragma unroll
  for (int i = 0; i < 16; ++i) { acc0[i] = 0.f; acc1[i] = 0.f; }
  float mrow = -1e30f;
  float rsum = 0.f;

  // LDS byte offsets: row = 32x+ql, col byte 32s+16h (same for K and V)
  int kofs[2][4];
#pragma unroll
  for (int x = 0; x < 2; ++x) {
    const int row = 32 * x + ql;
    const int sw  = SWZ(row);
#pragma unroll
    for (int s = 0; s < 4; ++s)
      kofs[x][s] = row * 128 + ((32 * s + 16 * h) ^ sw);
  }

  // P-pack: 8 exp'd scores -> PV B-frag via lane+-32 exchange (T12)
  auto mkfrag = [&](float p0, float p1, float p2, float p3,
                    float p4, float p5, float p6, float p7) -> bf16x8 {
    uint a0 = cvtpk(p0, p1), a1 = cvtpk(p2, p3);
    uint b0 = cvtpk(p4, p5), b1 = cvtpk(p6, p7);
    uint ta0 = __shfl_xor(a0, 32), ta1 = __shfl_xor(a1, 32);
    uint tb0 = __shfl_xor(b0, 32), tb1 = __shfl_xor(b1, 32);
    uint4 wv;
    wv.x = h ? tb0 : a0;
    wv.y = h ? tb1 : a1;
    wv.z = h ? b0  : ta0;
    wv.w = h ? b1  : ta1;
    return __builtin_bit_cast(bf16x8, wv);
  };

  // staging decomposition (fallback path)
  const int kr0 = tid >> 3, kc8 = tid & 7;
  const int vr = (tid >> 4) * 4, vc = (tid & 15) * 4;

  for (int t = 0; t < NT; ++t) {
    // ---- stage tile t ----
    if (PRE) {
      const char* ksrc = kws + ((size_t)bh * NT + t) * TILE_BYTES;
      const char* vsrc = vws + ((size_t)bh * NT + t) * TILE_BYTES;
#pragma unroll
      for (int c = 0; c < 2; ++c) {
        const int off = (w + c * 4) * 1024 + lane * 16;
        gload16(ksrc + off, (char*)kb + off);
        gload16(vsrc + off, (char*)vb + off);
      }
    } else {
#pragma unroll
      for (int hh = 0; hh < 2; ++hh) {
        const int row = kr0 + 32 * hh;
        const float* kp = Kb + (size_t)(t * KVBLK + row) * DH + kc8 * 8;
        float4 a = *(const float4*)kp;
        float4 b = *(const float4*)(kp + 4);
        ushort8v pk;
        pk[0]=bfb(a.x); pk[1]=bfb(a.y); pk[2]=bfb(a.z); pk[3]=bfb(a.w);
        pk[4]=bfb(b.x); pk[5]=bfb(b.y); pk[6]=bfb(b.z); pk[7]=bfb(b.w);
        *(ushort8v*)((char*)kb + row * 128 + ((kc8 * 16) ^ SWZ(row))) = pk;
      }
      float rr[4][4];
#pragma unroll
      for (int i = 0; i < 4; ++i)
        *(float4*)rr[i] = *(const float4*)(Vb + (size_t)(t * KVBLK + vr + i) * DH + vc);
#pragma unroll
      for (int c = 0; c < 4; ++c) {
        const int d = vc + c;
        ushort4v p4;
        p4[0]=bfb(rr[0][c]); p4[1]=bfb(rr[1][c]);
        p4[2]=bfb(rr[2][c]); p4[3]=bfb(rr[3][c]);
        *(ushort4v*)((char*)vb + d * 128 + ((vr * 2) ^ SWZ(d))) = p4;
      }
    }
    __syncthreads();

    // ---- S^T = K Q^T : 2 kv-tiles x 4 k-steps (8 mfma_32x32x16) ----
    f32x16 sc0, sc1;
#pragma unroll
    for (int i = 0; i < 16; ++i) { sc0[i] = 0.f; sc1[i] = 0.f; }

    __builtin_amdgcn_s_setprio(1);
#pragma unroll
    for (int s = 0; s < 4; ++s) {
      bf16x8 k0 = *(const bf16x8*)((const char*)kb + kofs[0][s]);
      bf16x8 k1 = *(const bf16x8*)((const char*)kb + kofs[1][s]);
      sc0 = __builtin_amdgcn_mfma_f32_32x32x16_bf16(k0, qf[s], sc0, 0,0,0);
      sc1 = __builtin_amdgcn_mfma_f32_32x32x16_bf16(k1, qf[s], sc1, 0,0,0);
    }
    __builtin_amdgcn_s_setprio(0);

    const bool allset = PRE ? (((fmask >> t) & 1u) != 0u) : false;
    if (!allset) {
      const size_t mo = (size_t)(q0 + w * 32 + ql) * S_LEN + t * KVBLK + 4 * h;
#pragma unroll
      for (int r = 0; r < 16; ++r) {
        const int cr = (r & 3) + 8 * (r >> 2);
        if (M[mo + cr] == 0)      sc0[r] = NEG;
        if (M[mo + 32 + cr] == 0) sc1[r] = NEG;
      }
    }

    // ---- in-register online softmax (serial chain) ----
    float lm = fmaxf(sc0[0], sc0[1]);
#pragma unroll
    for (int i = 2; i < 16; ++i) lm = fmaxf(lm, sc0[i]);
#pragma unroll
    for (int i = 0; i < 16; ++i) lm = fmaxf(lm, sc1[i]);
    lm = fmaxf(lm, __shfl_xor(lm, 32));

    if (!__all(lm - mrow <= THR)) {      // defer-max (T13)
      const float mnew = fmaxf(mrow, lm);
      const float corr = __builtin_amdgcn_exp2f(mrow - mnew);
      rsum *= corr;
      acc0 *= corr;
      acc1 *= corr;
      mrow = mnew;
    }

    float ps = 0.f;
#pragma unroll
    for (int i = 0; i < 16; ++i) {
      sc0[i] = __builtin_amdgcn_exp2f(sc0[i] - mrow); ps += sc0[i];
      sc1[i] = __builtin_amdgcn_exp2f(sc1[i] - mrow); ps += sc1[i];
    }
    rsum += ps;

    // ---- P -> PV B-frags, fully in-register (T12) ----
    bf16x8 pf[4];
    pf[0] = mkfrag(sc0[0], sc0[1], sc0[2],  sc0[3],  sc0[4],  sc0[5],  sc0[6],  sc0[7]);
    pf[1] = mkfrag(sc0[8], sc0[9], sc0[10], sc0[11], sc0[12], sc0[13], sc0[14], sc0[15]);
    pf[2] = mkfrag(sc1[0], sc1[1], sc1[2],  sc1[3],  sc1[4],  sc1[5],  sc1[6],  sc1[7]);
    pf[3] = mkfrag(sc1[8], sc1[9], sc1[10], sc1[11], sc1[12], sc1[13], sc1[14], sc1[15]);

    // ---- O^T += V^T P^T : 2 d-tiles x 4 kv-steps ----
    __builtin_amdgcn_s_setprio(1);
#pragma unroll
    for (int s = 0; s < 4; ++s) {
      bf16x8 v0 = *(const bf16x8*)((const char*)vb + kofs[0][s]);
      bf16x8 v1 = *(const bf16x8*)((const char*)vb + kofs[1][s]);
      acc0 = __builtin_amdgcn_mfma_f32_32x32x16_bf16(v0, pf[s], acc0, 0,0,0);
      acc1 = __builtin_amdgcn_mfma_f32_32x32x16_bf16(v1, pf[s], acc1, 0,0,0);
    }
    __builtin_amdgcn_s_setprio(0);

    __syncthreads();
  }

  // ---- epilogue: O[q][d] = acc / rsum ----
  rsum += __shfl_xor(rsum, 32);
  const float inv = 1.0f / rsum;
  float* Ob = O + ((size_t)bh * S_LEN + q0 + w * 32 + ql) * DH + 4 * h;
#pragma unroll
  for (int g = 0; g < 4; ++g) {
    float4 o0 = { acc0[4*g+0]*inv, acc0[4*g+1]*inv, acc0[4*g+2]*inv, acc0[4*g+3]*inv };
    float4 o1 = { acc1[4*g+0]*inv, acc1[4*g+1]*inv, acc1[4*g+2]*inv, acc1[4*g+3]*inv };
    *(float4*)(Ob + 8 * g)      = o0;
    *(float4*)(Ob + 32 + 8 * g) = o1;
  }
}

extern "C" void kernel_launch(void* const* d_in, const int* in_sizes, int n_in,
                              void* d_out, int out_size, void* d_ws, size_t ws_size,
                              hipStream_t stream)
{
  const float* Q = (const float*)d_in[0];
  const float* K = (const float*)d_in[1];
  const float* V = (const float*)d_in[2];
  const int*   M = (const int*)d_in[3];
  float* O = (float*)d_out;

  const size_t need = 4096 + 2 * KV_BYTES;
  const bool pre = (d_ws != nullptr) && (ws_size >= need);

  dim3 grid(S_LEN / QBLK, 4 * 16);   // 16 q-blocks x 64 (b,h) = 1024 wgs
  if (pre) {
    uint* F   = (uint*)d_ws;          // 32*8 disjoint words, fully overwritten
    char* kws = (char*)d_ws + 4096;
    char* vws = kws + KV_BYTES;
    cvt_kv<<<dim3(NT, 64), 256, 0, stream>>>(K, V, M, kws, vws, F);
    attn_fwd<true><<<grid, NWAVE * 64, 0, stream>>>(Q, K, V, M, F, kws, vws, O);
  } else {
    attn_fwd<false><<<grid, NWAVE * 64, 0, stream>>>(Q, K, V, M, nullptr, nullptr, nullptr, O);
  }
}